// Round 1
// baseline (982.883 us; speedup 1.0000x reference)
//
#include <hip/hip_runtime.h>

#define NNODES 50000
#define NEDGES 800000
#define NGRAPHS 128
#define HIDF 64

// ---------------------------------------------------------------------------
// Kernel 1: embedding lookup. h[n][c] = zb[n][c] = emb[feats[n]][c]
// emb table is 25.6 KB -> L1/L2 resident. Coalesced writes.
// ---------------------------------------------------------------------------
__global__ __launch_bounds__(256) void k_embed(const int* __restrict__ feats,
                                               const float* __restrict__ emb,
                                               float* __restrict__ h,
                                               float* __restrict__ zb) {
    int t = blockIdx.x * blockDim.x + threadIdx.x;
    if (t >= NNODES * HIDF) return;
    int n = t >> 6;
    int c = t & 63;
    float v = emb[feats[n] * HIDF + c];
    h[t] = v;
    zb[t] = v;
}

// ---------------------------------------------------------------------------
// Kernel 2: edge scatter-add. zb[dst[e]][c] += h[src[e]][c]
// One wave per edge (lane = channel): src-row gather is one coalesced 256B
// transaction; 64 atomics go to 64 consecutive addresses (no same-address
// conflict inside a wave). Grid-stride so each wave handles ~8 edges.
// ---------------------------------------------------------------------------
__global__ __launch_bounds__(256) void k_scatter(const int* __restrict__ src,
                                                 const int* __restrict__ dst,
                                                 const float* __restrict__ h,
                                                 float* zb) {
    int wave = (blockIdx.x * blockDim.x + threadIdx.x) >> 6;
    int c = threadIdx.x & 63;
    int nwaves = (gridDim.x * blockDim.x) >> 6;
    for (int e = wave; e < NEDGES; e += nwaves) {
        int s = src[e];
        int d = dst[e];
        atomicAdd(&zb[d * HIDF + c], h[s * HIDF + c]);
    }
}

// ---------------------------------------------------------------------------
// Kernel 3: fused GIN apply_func.  Wave per node, lane = output channel.
//   z2 = relu(z @ W1 + b1);  hnext = z2 @ W2 + b2
// Weights staged in LDS (32 KB), z broadcast across lanes via __shfl.
// FINAL=0: write hnext to BOTH h (read-only side of next scatter) and zb
//          (accumulator side), which replaces memset+add of a separate agg.
// FINAL=1: fold SumPool + head:  out[gid[n]] += dot(hnext, Wr)   (pool and
//          the linear head commute), so h3 is never materialized.
// ---------------------------------------------------------------------------
template <int FINAL>
__global__ __launch_bounds__(256) void k_mlp(const float* zb_in,
                                             const float* __restrict__ W1,
                                             const float* __restrict__ b1,
                                             const float* __restrict__ W2,
                                             const float* __restrict__ b2,
                                             float* h_out, float* zb_out,
                                             const float* __restrict__ Wr,
                                             const int* __restrict__ gid,
                                             float* out) {
    __shared__ float sW1[HIDF * HIDF];
    __shared__ float sW2[HIDF * HIDF];
    __shared__ float sb1[HIDF], sb2[HIDF];

    // cooperative vectorized weight load: 2 * 4096 floats
    for (int i = threadIdx.x; i < (HIDF * HIDF) / 4; i += 256) {
        ((float4*)sW1)[i] = ((const float4*)W1)[i];
        ((float4*)sW2)[i] = ((const float4*)W2)[i];
    }
    if (threadIdx.x < HIDF) {
        sb1[threadIdx.x] = b1[threadIdx.x];
        sb2[threadIdx.x] = b2[threadIdx.x];
    }
    __syncthreads();

    int wid = threadIdx.x >> 6;
    int lane = threadIdx.x & 63;

    for (int node = blockIdx.x * 4 + wid; node < NNODES; node += gridDim.x * 4) {
        float zin = zb_in[node * HIDF + lane];

        float acc = sb1[lane];
#pragma unroll
        for (int k = 0; k < HIDF; ++k)
            acc = fmaf(__shfl(zin, k), sW1[k * HIDF + lane], acc);
        acc = fmaxf(acc, 0.f);

        float acc2 = sb2[lane];
#pragma unroll
        for (int k = 0; k < HIDF; ++k)
            acc2 = fmaf(__shfl(acc, k), sW2[k * HIDF + lane], acc2);

        if (FINAL) {
            float v = acc2 * Wr[lane];
#pragma unroll
            for (int off = 32; off >= 1; off >>= 1) v += __shfl_xor(v, off);
            if (lane == 0) atomicAdd(&out[gid[node]], v);
        } else {
            h_out[node * HIDF + lane] = acc2;
            zb_out[node * HIDF + lane] = acc2;
        }
    }
}

// ---------------------------------------------------------------------------
extern "C" void kernel_launch(void* const* d_in, const int* in_sizes, int n_in,
                              void* d_out, int out_size, void* d_ws, size_t ws_size,
                              hipStream_t stream) {
    const int*   feats = (const int*)d_in[0];
    const int*   src   = (const int*)d_in[1];
    const int*   dst   = (const int*)d_in[2];
    const int*   gid   = (const int*)d_in[3];
    const float* emb   = (const float*)d_in[4];
    const float* W1    = (const float*)d_in[5];
    const float* b1    = (const float*)d_in[6];
    const float* W2    = (const float*)d_in[7];
    const float* b2    = (const float*)d_in[8];
    const float* Wr    = (const float*)d_in[9];
    float* out = (float*)d_out;

    float* h  = (float*)d_ws;                       // 50000*64 f32 = 12.8 MB
    float* zb = h + (size_t)NNODES * HIDF;          // 12.8 MB

    // h = zb = emb[feats]
    k_embed<<<(NNODES * HIDF + 255) / 256, 256, 0, stream>>>(feats, emb, h, zb);

    for (int l = 0; l < 3; ++l) {
        // zb[dst] += h[src]   (zb already holds h -> zb becomes h + agg)
        k_scatter<<<25000, 256, 0, stream>>>(src, dst, h, zb);

        if (l < 2) {
            k_mlp<0><<<1024, 256, 0, stream>>>(zb, W1 + l * HIDF * HIDF, b1 + l * HIDF,
                                               W2 + l * HIDF * HIDF, b2 + l * HIDF,
                                               h, zb, nullptr, nullptr, nullptr);
        } else {
            hipMemsetAsync(out, 0, NGRAPHS * sizeof(float), stream);
            k_mlp<1><<<1024, 256, 0, stream>>>(zb, W1 + l * HIDF * HIDF, b1 + l * HIDF,
                                               W2 + l * HIDF * HIDF, b2 + l * HIDF,
                                               nullptr, nullptr, Wr, gid, out);
        }
    }
}

// Round 4
// 699.834 us; speedup vs baseline: 1.4045x; 1.4045x over previous
//
#include <hip/hip_runtime.h>

#define NNODES 50000
#define NEDGES 800000
#define NGRAPHS 128
#define HIDF 64
#define ROWSTR 68  // padded LDS row stride (floats): 16B-aligned, spreads banks

// ---------------------------------------------------------------------------
// Kernel 1: embedding lookup. h[n][c] = zb[n][c] = emb[feats[n]][c]
// (zb write is dead in the CSR path but kept so the atomic fallback works.)
// ---------------------------------------------------------------------------
__global__ __launch_bounds__(256) void k_embed(const int* __restrict__ feats,
                                               const float* __restrict__ emb,
                                               float* __restrict__ h,
                                               float* __restrict__ zb) {
    int t = blockIdx.x * blockDim.x + threadIdx.x;
    if (t >= NNODES * HIDF) return;
    int n = t >> 6;
    int c = t & 63;
    float v = emb[feats[n] * HIDF + c];
    h[t] = v;
    zb[t] = v;
}

// ---------------------------------------------------------------------------
// Fallback scatter (used only if ws_size can't fit the CSR arrays):
// zb[dst[e]][c] += h[src[e]][c], wave per edge, lane = channel.
// ---------------------------------------------------------------------------
__global__ __launch_bounds__(256) void k_scatter(const int* __restrict__ src,
                                                 const int* __restrict__ dst,
                                                 const float* __restrict__ h,
                                                 float* zb) {
    int wave = (blockIdx.x * blockDim.x + threadIdx.x) >> 6;
    int c = threadIdx.x & 63;
    int nwaves = (gridDim.x * blockDim.x) >> 6;
    for (int e = wave; e < NEDGES; e += nwaves) {
        int s = src[e];
        int d = dst[e];
        atomicAdd(&zb[d * HIDF + c], h[s * HIDF + c]);
    }
}

// ---------------------------------------------------------------------------
// CSR build (once per launch, reused by all 3 layers).
// ---------------------------------------------------------------------------
__global__ __launch_bounds__(256) void k_hist(const int* __restrict__ dst,
                                              int* __restrict__ deg) {
    int t = blockIdx.x * blockDim.x + threadIdx.x;
    if (t < NEDGES) atomicAdd(&deg[dst[t]], 1);
}

// Single-block exclusive prefix sum over 50000 degrees -> off[0..NNODES].
__global__ __launch_bounds__(1024) void k_scan(const int* __restrict__ deg,
                                               int* __restrict__ off) {
    __shared__ int buf[1024];
    __shared__ int carry;
    const int tid = threadIdx.x;
    if (tid == 0) carry = 0;
    for (int base = 0; base < NNODES; base += 1024) {
        int i = base + tid;
        int v = (i < NNODES) ? deg[i] : 0;
        __syncthreads();              // protect buf/carry from prev iter
        buf[tid] = v;
        __syncthreads();
#pragma unroll
        for (int s = 1; s < 1024; s <<= 1) {   // Hillis-Steele inclusive scan
            int t2 = (tid >= s) ? buf[tid - s] : 0;
            __syncthreads();
            buf[tid] += t2;
            __syncthreads();
        }
        if (i < NNODES) off[i] = carry + buf[tid] - v;  // exclusive
        __syncthreads();              // all carry reads done
        if (tid == 0) carry += buf[1023];
    }
    __syncthreads();
    if (tid == 0) off[NNODES] = carry;
}

__global__ __launch_bounds__(256) void k_bucket(const int* __restrict__ src,
                                                const int* __restrict__ dst,
                                                int* __restrict__ cursor,
                                                int* __restrict__ csr) {
    int t = blockIdx.x * blockDim.x + threadIdx.x;
    if (t < NEDGES) {
        int pos = atomicAdd(&cursor[dst[t]], 1);
        csr[pos] = src[t];
    }
}

// ---------------------------------------------------------------------------
// Pull-mode aggregate: zb[n] = h[n] + sum_{e in csr[off[n]:off[n+1])} h[csr[e]]
// Wave per node, lane = channel: each edge gather is one coalesced 256B read
// (L2/L3-resident), accumulate in register, ONE plain store. Zero atomics.
// ---------------------------------------------------------------------------
__global__ __launch_bounds__(256) void k_agg(const int* __restrict__ off,
                                             const int* __restrict__ csr,
                                             const float* __restrict__ h,
                                             float* __restrict__ zb) {
    int wave = (blockIdx.x * blockDim.x + threadIdx.x) >> 6;
    int c = threadIdx.x & 63;
    if (wave >= NNODES) return;
    const int n = wave;
    int e0 = off[n], e1 = off[n + 1];
    float acc = h[(size_t)n * HIDF + c];
    for (int e = e0; e < e1; ++e)
        acc += h[(size_t)csr[e] * HIDF + c];
    zb[(size_t)n * HIDF + c] = acc;
}

// ---------------------------------------------------------------------------
// Kernel: fused GIN apply_func, thread-per-node (unchanged from R2).
//   z2 = relu(z @ W1 + b1);  hnext = z2 @ W2 + b2
// acc[64] in VGPRs = 64 independent FMA chains (R1's shfl chain: VALUBusy 5%).
// FINAL=1 fuses SumPool + regression head via LDS pool + sparse atomic flush.
// ---------------------------------------------------------------------------
template <int FINAL>
__global__ __launch_bounds__(64) void k_mlp(const float* __restrict__ zb_in,
                                            const float* __restrict__ W1,
                                            const float* __restrict__ b1,
                                            const float* __restrict__ W2,
                                            const float* __restrict__ b2,
                                            float* __restrict__ h_out,
                                            float* __restrict__ zb_out,
                                            const float* __restrict__ Wr,
                                            const int* __restrict__ gid,
                                            float* __restrict__ out) {
    __shared__ float zt[64 * ROWSTR];       // 17.0 KB activation tile
    __shared__ float sW1[HIDF * HIDF];      // 16 KB
    __shared__ float sW2[HIDF * HIDF];      // 16 KB
    __shared__ float sb[3 * HIDF];          // b1 | b2 | Wr
    __shared__ float pool[NGRAPHS];

    const int lane = threadIdx.x;           // 0..63
    const int base = blockIdx.x * 64;
    const int node = base + lane;
    const bool valid = node < NNODES;

    // ---- cooperative staging (coalesced global, aligned LDS) ----
    for (int i = lane; i < 64 * 16; i += 64) {
        int row = i >> 4;
        int c4 = (i & 15) * 4;
        if (base + row < NNODES) {
            float4 v = *(const float4*)&zb_in[(size_t)(base + row) * HIDF + c4];
            *(float4*)&zt[row * ROWSTR + c4] = v;
        }
    }
    for (int i = lane; i < 1024; i += 64) {
        ((float4*)sW1)[i] = ((const float4*)W1)[i];
        ((float4*)sW2)[i] = ((const float4*)W2)[i];
    }
    sb[lane] = b1[lane];
    sb[64 + lane] = b2[lane];
    if (FINAL) {
        sb[128 + lane] = Wr[lane];
        pool[lane] = 0.f;
        pool[64 + lane] = 0.f;
    }
    __syncthreads();

    const int zrow = lane * ROWSTR;

    // ---- layer A: z2 = relu(z @ W1 + b1) ----
    float acc[HIDF];
#pragma unroll
    for (int j = 0; j < HIDF; ++j) acc[j] = sb[j];

    for (int k4 = 0; k4 < HIDF; k4 += 4) {
        float4 zq = *(const float4*)&zt[zrow + k4];
#pragma unroll
        for (int kk = 0; kk < 4; ++kk) {
            float zk = (kk == 0) ? zq.x : (kk == 1) ? zq.y : (kk == 2) ? zq.z : zq.w;
            const float* wrow = &sW1[(k4 + kk) * HIDF];
#pragma unroll
            for (int j = 0; j < HIDF; ++j) acc[j] = fmaf(zk, wrow[j], acc[j]);
        }
    }
#pragma unroll
    for (int j = 0; j < HIDF; ++j) acc[j] = fmaxf(acc[j], 0.f);

    // write z2 to own LDS row (same-thread read-back; no barrier needed)
#pragma unroll
    for (int j4 = 0; j4 < HIDF; j4 += 4)
        *(float4*)&zt[zrow + j4] = make_float4(acc[j4], acc[j4 + 1], acc[j4 + 2], acc[j4 + 3]);

    // ---- layer B: hnext = z2 @ W2 + b2 ----
    float acc2[HIDF];
#pragma unroll
    for (int j = 0; j < HIDF; ++j) acc2[j] = sb[64 + j];

    for (int k4 = 0; k4 < HIDF; k4 += 4) {
        float4 zq = *(const float4*)&zt[zrow + k4];
#pragma unroll
        for (int kk = 0; kk < 4; ++kk) {
            float zk = (kk == 0) ? zq.x : (kk == 1) ? zq.y : (kk == 2) ? zq.z : zq.w;
            const float* wrow = &sW2[(k4 + kk) * HIDF];
#pragma unroll
            for (int j = 0; j < HIDF; ++j) acc2[j] = fmaf(zk, wrow[j], acc2[j]);
        }
    }

    if (FINAL) {
        // fused SumPool + head: out[gid[n]] += dot(hnext, Wr)
        float v = 0.f;
#pragma unroll
        for (int j = 0; j < HIDF; ++j) v = fmaf(acc2[j], sb[128 + j], v);
        if (valid) atomicAdd(&pool[gid[node]], v);
        __syncthreads();
        float p0 = pool[lane], p1 = pool[64 + lane];
        if (p0 != 0.f) atomicAdd(&out[lane], p0);
        if (p1 != 0.f) atomicAdd(&out[64 + lane], p1);
    } else {
        // route through LDS for coalesced global stores
#pragma unroll
        for (int j4 = 0; j4 < HIDF; j4 += 4)
            *(float4*)&zt[zrow + j4] = make_float4(acc2[j4], acc2[j4 + 1], acc2[j4 + 2], acc2[j4 + 3]);
        __syncthreads();
        for (int i = lane; i < 64 * 16; i += 64) {
            int row = i >> 4;
            int c4 = (i & 15) * 4;
            if (base + row < NNODES) {
                float4 v = *(const float4*)&zt[row * ROWSTR + c4];
                size_t o = (size_t)(base + row) * HIDF + c4;
                *(float4*)&h_out[o] = v;
                *(float4*)&zb_out[o] = v;
            }
        }
    }
}

// ---------------------------------------------------------------------------
extern "C" void kernel_launch(void* const* d_in, const int* in_sizes, int n_in,
                              void* d_out, int out_size, void* d_ws, size_t ws_size,
                              hipStream_t stream) {
    const int*   feats = (const int*)d_in[0];
    const int*   src   = (const int*)d_in[1];
    const int*   dst   = (const int*)d_in[2];
    const int*   gid   = (const int*)d_in[3];
    const float* emb   = (const float*)d_in[4];
    const float* W1    = (const float*)d_in[5];
    const float* b1    = (const float*)d_in[6];
    const float* W2    = (const float*)d_in[7];
    const float* b2    = (const float*)d_in[8];
    const float* Wr    = (const float*)d_in[9];
    float* out = (float*)d_out;

    float* h  = (float*)d_ws;                         // 12.8 MB
    float* zb = h + (size_t)NNODES * HIDF;            // 12.8 MB
    int* deg    = (int*)(zb + (size_t)NNODES * HIDF); // 0.2 MB
    int* off    = deg + NNODES;                       // 0.2 MB
    int* cursor = off + NNODES + 1;                   // 0.2 MB
    int* csr    = cursor + NNODES;                    // 3.2 MB

    size_t need = (size_t)(2 * NNODES * HIDF) * sizeof(float) +
                  (size_t)(3 * NNODES + 1 + NEDGES) * sizeof(int);
    const bool use_csr = ws_size >= need;   // constant across calls: capture-safe

    k_embed<<<(NNODES * HIDF + 255) / 256, 256, 0, stream>>>(feats, emb, h, zb);

    if (use_csr) {
        hipMemsetAsync(deg, 0, NNODES * sizeof(int), stream);
        k_hist<<<(NEDGES + 255) / 256, 256, 0, stream>>>(dst, deg);
        k_scan<<<1, 1024, 0, stream>>>(deg, off);
        hipMemcpyAsync(cursor, off, NNODES * sizeof(int),
                       hipMemcpyDeviceToDevice, stream);
        k_bucket<<<(NEDGES + 255) / 256, 256, 0, stream>>>(src, dst, cursor, csr);
    }

    const int mlp_grid = (NNODES + 63) / 64;          // 782

    for (int l = 0; l < 3; ++l) {
        if (use_csr)
            k_agg<<<(NNODES * HIDF + 255) / 256, 256, 0, stream>>>(off, csr, h, zb);
        else
            k_scatter<<<25000, 256, 0, stream>>>(src, dst, h, zb);

        if (l < 2) {
            k_mlp<0><<<mlp_grid, 64, 0, stream>>>(zb, W1 + l * HIDF * HIDF, b1 + l * HIDF,
                                                  W2 + l * HIDF * HIDF, b2 + l * HIDF,
                                                  h, zb, nullptr, nullptr, nullptr);
        } else {
            hipMemsetAsync(out, 0, NGRAPHS * sizeof(float), stream);
            k_mlp<1><<<mlp_grid, 64, 0, stream>>>(zb, W1 + l * HIDF * HIDF, b1 + l * HIDF,
                                                  W2 + l * HIDF * HIDF, b2 + l * HIDF,
                                                  nullptr, nullptr, Wr, gid, out);
        }
    }
}

// Round 5
// 446.743 us; speedup vs baseline: 2.2001x; 1.5665x over previous
//
#include <hip/hip_runtime.h>

#define NNODES 50000
#define NEDGES 800000
#define NGRAPHS 128
#define HIDF 64
#define ZSTR 128            // zT row stride (floats); banks fixed by XOR swizzle
#define NBLK 196            // ceil(50000/256) scan blocks

// Swizzled transposed-activation index: channel c, node-in-block n.
// XOR spreads the (c>>3) group across banks; preserves 16B alignment (n%4==0).
__device__ __forceinline__ int zidx(int c, int n) {
    return c * ZSTR + (n ^ ((((c) >> 3) & 7) << 2));
}

// ---------------------------------------------------------------------------
// Fallback-only kernels (used if ws_size too small for CSR; never expected).
// ---------------------------------------------------------------------------
__global__ __launch_bounds__(256) void k_embed(const int* __restrict__ feats,
                                               const float* __restrict__ emb,
                                               float* __restrict__ h,
                                               float* __restrict__ zb) {
    int t = blockIdx.x * blockDim.x + threadIdx.x;
    if (t >= NNODES * HIDF) return;
    float v = emb[feats[t >> 6] * HIDF + (t & 63)];
    h[t] = v;
    zb[t] = v;
}

__global__ __launch_bounds__(256) void k_scatter(const int* __restrict__ src,
                                                 const int* __restrict__ dst,
                                                 const float* __restrict__ h,
                                                 float* zb) {
    int wave = (blockIdx.x * blockDim.x + threadIdx.x) >> 6;
    int c = threadIdx.x & 63;
    int nwaves = (gridDim.x * blockDim.x) >> 6;
    for (int e = wave; e < NEDGES; e += nwaves)
        atomicAdd(&zb[dst[e] * HIDF + c], h[src[e] * HIDF + c]);
}

// ---------------------------------------------------------------------------
// CSR build: hist -> 3-stage multi-block exclusive scan -> bucket fill.
// (R4's single-block scan was 88us at 0.17% occupancy -- top kernel.)
// ---------------------------------------------------------------------------
__global__ __launch_bounds__(256) void k_hist(const int* __restrict__ dst,
                                              int* __restrict__ deg) {
    int t = blockIdx.x * blockDim.x + threadIdx.x;
    if (t < NEDGES) atomicAdd(&deg[dst[t]], 1);
}

__global__ __launch_bounds__(256) void k_scan1(const int* __restrict__ deg,
                                               int* __restrict__ off,
                                               int* __restrict__ bsum) {
    __shared__ int buf[256];
    const int t = threadIdx.x;
    int i = blockIdx.x * 256 + t;
    int v = (i < NNODES) ? deg[i] : 0;
    buf[t] = v;
    __syncthreads();
#pragma unroll
    for (int s = 1; s < 256; s <<= 1) {
        int add = (t >= s) ? buf[t - s] : 0;
        __syncthreads();
        buf[t] += add;
        __syncthreads();
    }
    if (i < NNODES) off[i] = buf[t] - v;          // block-local exclusive
    if (t == 255) bsum[blockIdx.x] = buf[255];
}

__global__ __launch_bounds__(256) void k_scan2(const int* __restrict__ bsum,
                                               int* __restrict__ bofs,
                                               int* __restrict__ off) {
    __shared__ int buf[256];
    const int t = threadIdx.x;
    int v = (t < NBLK) ? bsum[t] : 0;
    buf[t] = v;
    __syncthreads();
#pragma unroll
    for (int s = 1; s < 256; s <<= 1) {
        int add = (t >= s) ? buf[t - s] : 0;
        __syncthreads();
        buf[t] += add;
        __syncthreads();
    }
    if (t < NBLK) bofs[t] = buf[t] - v;           // exclusive block offsets
    if (t == 255) off[NNODES] = buf[255];         // total = NEDGES
}

__global__ __launch_bounds__(256) void k_scan3(int* __restrict__ off,
                                               const int* __restrict__ bofs,
                                               int* __restrict__ cursor) {
    int i = blockIdx.x * 256 + threadIdx.x;
    if (i < NNODES) {
        int o = off[i] + bofs[blockIdx.x];
        off[i] = o;
        cursor[i] = o;                            // bucket cursors (no memcpy)
    }
}

__global__ __launch_bounds__(256) void k_bucket(const int* __restrict__ src,
                                                const int* __restrict__ dst,
                                                int* __restrict__ cursor,
                                                int* __restrict__ csr) {
    int t = blockIdx.x * blockDim.x + threadIdx.x;
    if (t < NEDGES) {
        int pos = atomicAdd(&cursor[dst[t]], 1);
        csr[pos] = src[t];
    }
}

// ---------------------------------------------------------------------------
// Pull-mode aggregate. Wave per node, lane = channel; each edge gather is one
// coalesced 256B read; ONE plain store; zero atomics.
// FIRST=1 reads emb[feats[.]] directly (emb 25.6KB L1-resident) -> k_embed
// and the h round-trip for layer 0 are eliminated.
// ---------------------------------------------------------------------------
template <int FIRST>
__global__ __launch_bounds__(256) void k_agg(const int* __restrict__ off,
                                             const int* __restrict__ csr,
                                             const float* __restrict__ hsrc,
                                             const int* __restrict__ feats,
                                             const float* __restrict__ emb,
                                             float* __restrict__ zb) {
    int wave = (blockIdx.x * blockDim.x + threadIdx.x) >> 6;
    int c = threadIdx.x & 63;
    if (wave >= NNODES) return;
    const int n = wave;
    int e0 = off[n], e1 = off[n + 1];
    float acc;
    if (FIRST) acc = emb[feats[n] * HIDF + c];
    else       acc = hsrc[(size_t)n * HIDF + c];
    for (int e = e0; e < e1; ++e) {
        int s = csr[e];
        if (FIRST) acc += emb[feats[s] * HIDF + c];
        else       acc += hsrc[(size_t)s * HIDF + c];
    }
    zb[(size_t)n * HIDF + c] = acc;
}

// ---------------------------------------------------------------------------
// Register-tiled fused MLP: 128 threads/block, 128 nodes/block.
// Thread (tx,ty) computes an 8-node x 8-channel tile: per k-step the wave
// issues 4 ds_read_b128 vs 64 wave-FMAs -> VALU-bound (R2's design issued
// 1024 broadcast b128/wave/layer -> LDS-issue bound).
// Activations transposed+XOR-swizzled in LDS; all accesses <=2-way (free).
// FINAL=1 fuses SumPool+head: tx-shfl reduce -> LDS pool -> sparse flush.
// ---------------------------------------------------------------------------
template <int FINAL, int WRITE_ZB>
__global__ __launch_bounds__(128) void k_mlp(const float* __restrict__ zin,
                                             const float* __restrict__ W1,
                                             const float* __restrict__ b1,
                                             const float* __restrict__ W2,
                                             const float* __restrict__ b2,
                                             float* __restrict__ h_out,
                                             float* __restrict__ zb_out,
                                             const float* __restrict__ Wr,
                                             const int* __restrict__ gid,
                                             float* __restrict__ out) {
    __shared__ float zt[HIDF * ZSTR];                 // 32 KB transposed acts
    __shared__ float sW1[HIDF * HIDF];                // 16 KB
    __shared__ float sW2[HIDF * HIDF];                // 16 KB
    __shared__ float sbb[3 * HIDF];                   // b1 | b2 | Wr
    __shared__ float pool[NGRAPHS];

    const int t = threadIdx.x;
    const int base = blockIdx.x * 128;

    // ---- stage weights (32 float4 per matrix per thread, L2-hot) ----
    for (int i = t; i < 1024; i += 128) {
        ((float4*)sW1)[i] = ((const float4*)W1)[i];
        ((float4*)sW2)[i] = ((const float4*)W2)[i];
    }
    if (t < 64) { sbb[t] = b1[t]; sbb[64 + t] = b2[t]; }
    if (FINAL) {
        if (t >= 64) sbb[64 + t] = Wr[t - 64];        // sbb[128..191]
        pool[t] = 0.f;
    }

    // ---- stage z transposed into swizzled LDS (2-way banks, coalesced gl) ----
    for (int it = 0; it < 16; ++it) {
        int idx = it * 128 + t;
        int nb = idx >> 4;                            // node-in-block 0..127
        int c0 = (idx & 15) * 4;
        int gn = base + nb;
        float4 v = (gn < NNODES) ? *(const float4*)&zin[(size_t)gn * HIDF + c0]
                                 : make_float4(0.f, 0.f, 0.f, 0.f);
        int sw = ((idx & 15) >> 1) << 2;              // == ((c0+i)>>3)<<2, i<4
        int nsw = nb ^ sw;
        zt[(c0 + 0) * ZSTR + nsw] = v.x;
        zt[(c0 + 1) * ZSTR + nsw] = v.y;
        zt[(c0 + 2) * ZSTR + nsw] = v.z;
        zt[(c0 + 3) * ZSTR + nsw] = v.w;
    }
    __syncthreads();

    const int tx = t & 7, ty = t >> 3;
    const int c0 = tx * 8, n0 = ty * 8;

    // ---- layer A: z2 = relu(z @ W1 + b1) ----
    float acc[8][8];
#pragma unroll
    for (int j = 0; j < 8; ++j) {
        float b = sbb[c0 + j];
#pragma unroll
        for (int i = 0; i < 8; ++i) acc[i][j] = b;
    }
    for (int k8 = 0; k8 < 8; ++k8) {
        const int x0 = n0 ^ (k8 << 2);                // hoisted swizzle
        const int x4 = (n0 + 4) ^ (k8 << 2);
#pragma unroll
        for (int kk = 0; kk < 8; ++kk) {
            int k = k8 * 8 + kk;
            float4 z0 = *(const float4*)&zt[k * ZSTR + x0];
            float4 z1 = *(const float4*)&zt[k * ZSTR + x4];
            float4 w0 = *(const float4*)&sW1[k * HIDF + c0];
            float4 w1 = *(const float4*)&sW1[k * HIDF + c0 + 4];
            float zv[8] = {z0.x, z0.y, z0.z, z0.w, z1.x, z1.y, z1.z, z1.w};
            float wv[8] = {w0.x, w0.y, w0.z, w0.w, w1.x, w1.y, w1.z, w1.w};
#pragma unroll
            for (int i = 0; i < 8; ++i)
#pragma unroll
                for (int j = 0; j < 8; ++j)
                    acc[i][j] = fmaf(zv[i], wv[j], acc[i][j]);
        }
    }
    __syncthreads();                                   // all zt reads done

    // write relu(z2) transposed back (banks 2-way via tx-swizzle)
    {
        const int wx0 = n0 ^ (tx << 2);               // ((c0+j)>>3)==tx
        const int wx4 = (n0 + 4) ^ (tx << 2);
#pragma unroll
        for (int j = 0; j < 8; ++j) {
            int c = c0 + j;
            *(float4*)&zt[c * ZSTR + wx0] =
                make_float4(fmaxf(acc[0][j], 0.f), fmaxf(acc[1][j], 0.f),
                            fmaxf(acc[2][j], 0.f), fmaxf(acc[3][j], 0.f));
            *(float4*)&zt[c * ZSTR + wx4] =
                make_float4(fmaxf(acc[4][j], 0.f), fmaxf(acc[5][j], 0.f),
                            fmaxf(acc[6][j], 0.f), fmaxf(acc[7][j], 0.f));
        }
    }
    __syncthreads();

    // ---- layer B: hnext = z2 @ W2 + b2 ----
    float acc2[8][8];
#pragma unroll
    for (int j = 0; j < 8; ++j) {
        float b = sbb[64 + c0 + j];
#pragma unroll
        for (int i = 0; i < 8; ++i) acc2[i][j] = b;
    }
    for (int k8 = 0; k8 < 8; ++k8) {
        const int x0 = n0 ^ (k8 << 2);
        const int x4 = (n0 + 4) ^ (k8 << 2);
#pragma unroll
        for (int kk = 0; kk < 8; ++kk) {
            int k = k8 * 8 + kk;
            float4 z0 = *(const float4*)&zt[k * ZSTR + x0];
            float4 z1 = *(const float4*)&zt[k * ZSTR + x4];
            float4 w0 = *(const float4*)&sW2[k * HIDF + c0];
            float4 w1 = *(const float4*)&sW2[k * HIDF + c0 + 4];
            float zv[8] = {z0.x, z0.y, z0.z, z0.w, z1.x, z1.y, z1.z, z1.w};
            float wv[8] = {w0.x, w0.y, w0.z, w0.w, w1.x, w1.y, w1.z, w1.w};
#pragma unroll
            for (int i = 0; i < 8; ++i)
#pragma unroll
                for (int j = 0; j < 8; ++j)
                    acc2[i][j] = fmaf(zv[i], wv[j], acc2[i][j]);
        }
    }

    if (FINAL) {
        // out[gid[n]] += dot(hnext[n], Wr): reduce 8 ch across tx via shfl.
#pragma unroll
        for (int i = 0; i < 8; ++i) {
            float pr = 0.f;
#pragma unroll
            for (int j = 0; j < 8; ++j) pr = fmaf(acc2[i][j], sbb[128 + c0 + j], pr);
#pragma unroll
            for (int o = 1; o < 8; o <<= 1) pr += __shfl_xor(pr, o);
            if (tx == 0) {
                int gn = base + n0 + i;
                if (gn < NNODES) atomicAdd(&pool[gid[gn]], pr);
            }
        }
        __syncthreads();
        float p = pool[t];
        if (p != 0.f) atomicAdd(&out[t], p);          // adding 0 is a no-op
    } else {
#pragma unroll
        for (int i = 0; i < 8; ++i) {
            int gn = base + n0 + i;
            if (gn < NNODES) {
                float4 lo = make_float4(acc2[i][0], acc2[i][1], acc2[i][2], acc2[i][3]);
                float4 hi = make_float4(acc2[i][4], acc2[i][5], acc2[i][6], acc2[i][7]);
                size_t o = (size_t)gn * HIDF + c0;
                *(float4*)&h_out[o] = lo;
                *(float4*)&h_out[o + 4] = hi;
                if (WRITE_ZB) { *(float4*)&zb_out[o] = lo; *(float4*)&zb_out[o + 4] = hi; }
            }
        }
    }
}

// ---------------------------------------------------------------------------
extern "C" void kernel_launch(void* const* d_in, const int* in_sizes, int n_in,
                              void* d_out, int out_size, void* d_ws, size_t ws_size,
                              hipStream_t stream) {
    const int*   feats = (const int*)d_in[0];
    const int*   src   = (const int*)d_in[1];
    const int*   dst   = (const int*)d_in[2];
    const int*   gid   = (const int*)d_in[3];
    const float* emb   = (const float*)d_in[4];
    const float* W1    = (const float*)d_in[5];
    const float* b1    = (const float*)d_in[6];
    const float* W2    = (const float*)d_in[7];
    const float* b2    = (const float*)d_in[8];
    const float* Wr    = (const float*)d_in[9];
    float* out = (float*)d_out;

    float* h  = (float*)d_ws;                          // 12.8 MB
    float* zb = h + (size_t)NNODES * HIDF;             // 12.8 MB
    int* deg    = (int*)(zb + (size_t)NNODES * HIDF);
    int* off    = deg + NNODES;                        // NNODES+1
    int* cursor = off + NNODES + 1;
    int* bsum   = cursor + NNODES;                     // NBLK
    int* bofs   = bsum + NBLK;                         // NBLK
    int* csr    = bofs + NBLK;                         // NEDGES

    size_t need = (size_t)(2 * NNODES * HIDF) * sizeof(float) +
                  (size_t)(3 * NNODES + 1 + 2 * NBLK + NEDGES) * sizeof(int);
    const bool use_csr = ws_size >= need;              // constant: capture-safe

    const int mlp_grid = (NNODES + 127) / 128;         // 391

    if (use_csr) {
        // ---- CSR build (once, reused by all 3 layers) ----
        hipMemsetAsync(deg, 0, NNODES * sizeof(int), stream);
        k_hist<<<(NEDGES + 255) / 256, 256, 0, stream>>>(dst, deg);
        k_scan1<<<NBLK, 256, 0, stream>>>(deg, off, bsum);
        k_scan2<<<1, 256, 0, stream>>>(bsum, bofs, off);
        k_scan3<<<NBLK, 256, 0, stream>>>(off, bofs, cursor);
        k_bucket<<<(NEDGES + 255) / 256, 256, 0, stream>>>(src, dst, cursor, csr);

        const int agg_grid = (NNODES * HIDF + 255) / 256;
        // layer 0 (agg reads emb directly; no k_embed)
        k_agg<1><<<agg_grid, 256, 0, stream>>>(off, csr, nullptr, feats, emb, zb);
        k_mlp<0, 0><<<mlp_grid, 128, 0, stream>>>(zb, W1, b1, W2, b2,
                                                  h, nullptr, nullptr, nullptr, nullptr);
        // layer 1
        k_agg<0><<<agg_grid, 256, 0, stream>>>(off, csr, h, nullptr, nullptr, zb);
        k_mlp<0, 0><<<mlp_grid, 128, 0, stream>>>(zb, W1 + 4096, b1 + 64, W2 + 4096, b2 + 64,
                                                  h, nullptr, nullptr, nullptr, nullptr);
        // layer 2 + fused pool/head
        k_agg<0><<<agg_grid, 256, 0, stream>>>(off, csr, h, nullptr, nullptr, zb);
        hipMemsetAsync(out, 0, NGRAPHS * sizeof(float), stream);
        k_mlp<1, 0><<<mlp_grid, 128, 0, stream>>>(zb, W1 + 8192, b1 + 128, W2 + 8192, b2 + 128,
                                                  nullptr, nullptr, Wr, gid, out);
    } else {
        // ---- fallback: atomic scatter path ----
        k_embed<<<(NNODES * HIDF + 255) / 256, 256, 0, stream>>>(feats, emb, h, zb);
        for (int l = 0; l < 3; ++l) {
            k_scatter<<<25000, 256, 0, stream>>>(src, dst, h, zb);
            if (l < 2) {
                k_mlp<0, 1><<<mlp_grid, 128, 0, stream>>>(zb, W1 + l * 4096, b1 + l * 64,
                                                          W2 + l * 4096, b2 + l * 64,
                                                          h, zb, nullptr, nullptr, nullptr);
            } else {
                hipMemsetAsync(out, 0, NGRAPHS * sizeof(float), stream);
                k_mlp<1, 0><<<mlp_grid, 128, 0, stream>>>(zb, W1 + l * 4096, b1 + l * 64,
                                                          W2 + l * 4096, b2 + l * 64,
                                                          nullptr, nullptr, Wr, gid, out);
            }
        }
    }
}

// Round 11
// 350.324 us; speedup vs baseline: 2.8056x; 1.2752x over previous
//
#include <hip/hip_runtime.h>

#define NNODES 50000
#define NEDGES 800000
#define NGRAPHS 128
#define HIDF 64
#define ZSTR 128            // zT row stride (floats); banks fixed by XOR swizzle
#define NBLK 196            // ceil(50000/256) scan blocks

// ---------------------------------------------------------------------------
// Fallback-only kernels (used if ws_size too small for CSR; never expected).
// ---------------------------------------------------------------------------
__global__ __launch_bounds__(256) void k_embed(const int* __restrict__ feats,
                                               const float* __restrict__ emb,
                                               float* __restrict__ h,
                                               float* __restrict__ zb) {
    int t = blockIdx.x * blockDim.x + threadIdx.x;
    if (t >= NNODES * HIDF) return;
    float v = emb[feats[t >> 6] * HIDF + (t & 63)];
    h[t] = v;
    zb[t] = v;
}

__global__ __launch_bounds__(256) void k_scatter(const int* __restrict__ src,
                                                 const int* __restrict__ dst,
                                                 const float* __restrict__ h,
                                                 float* zb) {
    int wave = (blockIdx.x * blockDim.x + threadIdx.x) >> 6;
    int c = threadIdx.x & 63;
    int nwaves = (gridDim.x * blockDim.x) >> 6;
    for (int e = wave; e < NEDGES; e += nwaves)
        atomicAdd(&zb[dst[e] * HIDF + c], h[src[e] * HIDF + c]);
}

// ---------------------------------------------------------------------------
// CSR build: hist -> 3-stage multi-block exclusive scan -> bucket fill.
// ---------------------------------------------------------------------------
__global__ __launch_bounds__(256) void k_hist(const int* __restrict__ dst,
                                              int* __restrict__ deg) {
    int t = blockIdx.x * blockDim.x + threadIdx.x;
    if (t < NEDGES) atomicAdd(&deg[dst[t]], 1);
}

__global__ __launch_bounds__(256) void k_scan1(const int* __restrict__ deg,
                                               int* __restrict__ off,
                                               int* __restrict__ bsum) {
    __shared__ int buf[256];
    const int t = threadIdx.x;
    int i = blockIdx.x * 256 + t;
    int v = (i < NNODES) ? deg[i] : 0;
    buf[t] = v;
    __syncthreads();
#pragma unroll
    for (int s = 1; s < 256; s <<= 1) {
        int add = (t >= s) ? buf[t - s] : 0;
        __syncthreads();
        buf[t] += add;
        __syncthreads();
    }
    if (i < NNODES) off[i] = buf[t] - v;          // block-local exclusive
    if (t == 255) bsum[blockIdx.x] = buf[255];
}

__global__ __launch_bounds__(256) void k_scan2(const int* __restrict__ bsum,
                                               int* __restrict__ bofs,
                                               int* __restrict__ off) {
    __shared__ int buf[256];
    const int t = threadIdx.x;
    int v = (t < NBLK) ? bsum[t] : 0;
    buf[t] = v;
    __syncthreads();
#pragma unroll
    for (int s = 1; s < 256; s <<= 1) {
        int add = (t >= s) ? buf[t - s] : 0;
        __syncthreads();
        buf[t] += add;
        __syncthreads();
    }
    if (t < NBLK) bofs[t] = buf[t] - v;           // exclusive block offsets
    if (t == 255) off[NNODES] = buf[255];         // total = NEDGES
}

__global__ __launch_bounds__(256) void k_scan3(int* __restrict__ off,
                                               const int* __restrict__ bofs,
                                               int* __restrict__ cursor) {
    int i = blockIdx.x * 256 + threadIdx.x;
    if (i < NNODES) {
        int o = off[i] + bofs[blockIdx.x];
        off[i] = o;
        cursor[i] = o;                            // bucket cursors (no memcpy)
    }
}

__global__ __launch_bounds__(256) void k_bucket(const int* __restrict__ src,
                                                const int* __restrict__ dst,
                                                int* __restrict__ cursor,
                                                int* __restrict__ csr) {
    int t = blockIdx.x * blockDim.x + threadIdx.x;
    if (t < NEDGES) {
        int pos = atomicAdd(&cursor[dst[t]], 1);
        csr[pos] = src[t];
    }
}

// ---------------------------------------------------------------------------
// Pull-mode aggregate, 4x software-pipelined.
// R5 profile: 75us, VALUBusy 12.8%, 1.26 TB/s (16% HBM), occ 66% ->
// latency-bound on the serial csr->h dependent chain (one ~L3 round-trip per
// edge). Unroll-by-4: the 4 csr entries share a cache line; the 4 row-gathers
// (8x128B lines) are independent and fly concurrently -> ~4x fewer latency
// stalls until the L3 BW floor.
// FIRST=1 reads emb[feats[.]] directly (emb 25.6KB L1-resident; no k_embed).
// ---------------------------------------------------------------------------
template <int FIRST>
__global__ __launch_bounds__(256) void k_agg(const int* __restrict__ off,
                                             const int* __restrict__ csr,
                                             const float* __restrict__ hsrc,
                                             const int* __restrict__ feats,
                                             const float* __restrict__ emb,
                                             float* __restrict__ zb) {
    int wave = (blockIdx.x * blockDim.x + threadIdx.x) >> 6;
    int c = threadIdx.x & 63;
    if (wave >= NNODES) return;
    const int n = wave;
    const int e0 = off[n], e1 = off[n + 1];

    float acc = FIRST ? emb[feats[n] * HIDF + c]
                      : hsrc[(size_t)n * HIDF + c];

    int e = e0;
    for (; e + 4 <= e1; e += 4) {
        int s0 = csr[e + 0], s1 = csr[e + 1], s2 = csr[e + 2], s3 = csr[e + 3];
        float v0, v1, v2, v3;
        if (FIRST) {
            v0 = emb[feats[s0] * HIDF + c];
            v1 = emb[feats[s1] * HIDF + c];
            v2 = emb[feats[s2] * HIDF + c];
            v3 = emb[feats[s3] * HIDF + c];
        } else {
            v0 = hsrc[(size_t)s0 * HIDF + c];
            v1 = hsrc[(size_t)s1 * HIDF + c];
            v2 = hsrc[(size_t)s2 * HIDF + c];
            v3 = hsrc[(size_t)s3 * HIDF + c];
        }
        acc += (v0 + v1) + (v2 + v3);
    }
    for (; e < e1; ++e) {
        int s = csr[e];
        acc += FIRST ? emb[feats[s] * HIDF + c]
                     : hsrc[(size_t)s * HIDF + c];
    }
    zb[(size_t)n * HIDF + c] = acc;
}

// ---------------------------------------------------------------------------
// Register-tiled fused MLP (unchanged from R5): 128 threads/block, 128 nodes.
// Thread (tx,ty) computes an 8-node x 8-channel tile -> VALU-bound.
// Activations transposed+XOR-swizzled in LDS; all accesses <=2-way (free).
// FINAL=1 fuses SumPool+head: tx-shfl reduce -> LDS pool -> sparse flush.
// ---------------------------------------------------------------------------
template <int FINAL, int WRITE_ZB>
__global__ __launch_bounds__(128) void k_mlp(const float* __restrict__ zin,
                                             const float* __restrict__ W1,
                                             const float* __restrict__ b1,
                                             const float* __restrict__ W2,
                                             const float* __restrict__ b2,
                                             float* __restrict__ h_out,
                                             float* __restrict__ zb_out,
                                             const float* __restrict__ Wr,
                                             const int* __restrict__ gid,
                                             float* __restrict__ out) {
    __shared__ float zt[HIDF * ZSTR];                 // 32 KB transposed acts
    __shared__ float sW1[HIDF * HIDF];                // 16 KB
    __shared__ float sW2[HIDF * HIDF];                // 16 KB
    __shared__ float sbb[3 * HIDF];                   // b1 | b2 | Wr
    __shared__ float pool[NGRAPHS];

    const int t = threadIdx.x;
    const int base = blockIdx.x * 128;

    for (int i = t; i < 1024; i += 128) {
        ((float4*)sW1)[i] = ((const float4*)W1)[i];
        ((float4*)sW2)[i] = ((const float4*)W2)[i];
    }
    if (t < 64) { sbb[t] = b1[t]; sbb[64 + t] = b2[t]; }
    if (FINAL) {
        if (t >= 64) sbb[64 + t] = Wr[t - 64];        // sbb[128..191]
        pool[t] = 0.f;
    }

    for (int it = 0; it < 16; ++it) {
        int idx = it * 128 + t;
        int nb = idx >> 4;                            // node-in-block 0..127
        int c0 = (idx & 15) * 4;
        int gn = base + nb;
        float4 v = (gn < NNODES) ? *(const float4*)&zin[(size_t)gn * HIDF + c0]
                                 : make_float4(0.f, 0.f, 0.f, 0.f);
        int sw = ((idx & 15) >> 1) << 2;              // == ((c0+i)>>3)<<2, i<4
        int nsw = nb ^ sw;
        zt[(c0 + 0) * ZSTR + nsw] = v.x;
        zt[(c0 + 1) * ZSTR + nsw] = v.y;
        zt[(c0 + 2) * ZSTR + nsw] = v.z;
        zt[(c0 + 3) * ZSTR + nsw] = v.w;
    }
    __syncthreads();

    const int tx = t & 7, ty = t >> 3;
    const int c0 = tx * 8, n0 = ty * 8;

    // ---- layer A: z2 = relu(z @ W1 + b1) ----
    float acc[8][8];
#pragma unroll
    for (int j = 0; j < 8; ++j) {
        float b = sbb[c0 + j];
#pragma unroll
        for (int i = 0; i < 8; ++i) acc[i][j] = b;
    }
    for (int k8 = 0; k8 < 8; ++k8) {
        const int x0 = n0 ^ (k8 << 2);                // hoisted swizzle
        const int x4 = (n0 + 4) ^ (k8 << 2);
#pragma unroll
        for (int kk = 0; kk < 8; ++kk) {
            int k = k8 * 8 + kk;
            float4 z0 = *(const float4*)&zt[k * ZSTR + x0];
            float4 z1 = *(const float4*)&zt[k * ZSTR + x4];
            float4 w0 = *(const float4*)&sW1[k * HIDF + c0];
            float4 w1 = *(const float4*)&sW1[k * HIDF + c0 + 4];
            float zv[8] = {z0.x, z0.y, z0.z, z0.w, z1.x, z1.y, z1.z, z1.w};
            float wv[8] = {w0.x, w0.y, w0.z, w0.w, w1.x, w1.y, w1.z, w1.w};
#pragma unroll
            for (int i = 0; i < 8; ++i)
#pragma unroll
                for (int j = 0; j < 8; ++j)
                    acc[i][j] = fmaf(zv[i], wv[j], acc[i][j]);
        }
    }
    __syncthreads();                                   // all zt reads done

    {
        const int wx0 = n0 ^ (tx << 2);               // ((c0+j)>>3)==tx
        const int wx4 = (n0 + 4) ^ (tx << 2);
#pragma unroll
        for (int j = 0; j < 8; ++j) {
            int c = c0 + j;
            *(float4*)&zt[c * ZSTR + wx0] =
                make_float4(fmaxf(acc[0][j], 0.f), fmaxf(acc[1][j], 0.f),
                            fmaxf(acc[2][j], 0.f), fmaxf(acc[3][j], 0.f));
            *(float4*)&zt[c * ZSTR + wx4] =
                make_float4(fmaxf(acc[4][j], 0.f), fmaxf(acc[5][j], 0.f),
                            fmaxf(acc[6][j], 0.f), fmaxf(acc[7][j], 0.f));
        }
    }
    __syncthreads();

    // ---- layer B: hnext = z2 @ W2 + b2 ----
    float acc2[8][8];
#pragma unroll
    for (int j = 0; j < 8; ++j) {
        float b = sbb[64 + c0 + j];
#pragma unroll
        for (int i = 0; i < 8; ++i) acc2[i][j] = b;
    }
    for (int k8 = 0; k8 < 8; ++k8) {
        const int x0 = n0 ^ (k8 << 2);
        const int x4 = (n0 + 4) ^ (k8 << 2);
#pragma unroll
        for (int kk = 0; kk < 8; ++kk) {
            int k = k8 * 8 + kk;
            float4 z0 = *(const float4*)&zt[k * ZSTR + x0];
            float4 z1 = *(const float4*)&zt[k * ZSTR + x4];
            float4 w0 = *(const float4*)&sW2[k * HIDF + c0];
            float4 w1 = *(const float4*)&sW2[k * HIDF + c0 + 4];
            float zv[8] = {z0.x, z0.y, z0.z, z0.w, z1.x, z1.y, z1.z, z1.w};
            float wv[8] = {w0.x, w0.y, w0.z, w0.w, w1.x, w1.y, w1.z, w1.w};
#pragma unroll
            for (int i = 0; i < 8; ++i)
#pragma unroll
                for (int j = 0; j < 8; ++j)
                    acc2[i][j] = fmaf(zv[i], wv[j], acc2[i][j]);
        }
    }

    if (FINAL) {
#pragma unroll
        for (int i = 0; i < 8; ++i) {
            float pr = 0.f;
#pragma unroll
            for (int j = 0; j < 8; ++j) pr = fmaf(acc2[i][j], sbb[128 + c0 + j], pr);
#pragma unroll
            for (int o = 1; o < 8; o <<= 1) pr += __shfl_xor(pr, o);
            if (tx == 0) {
                int gn = base + n0 + i;
                if (gn < NNODES) atomicAdd(&pool[gid[gn]], pr);
            }
        }
        __syncthreads();
        float p = pool[t];
        if (p != 0.f) atomicAdd(&out[t], p);          // adding 0 is a no-op
    } else {
#pragma unroll
        for (int i = 0; i < 8; ++i) {
            int gn = base + n0 + i;
            if (gn < NNODES) {
                float4 lo = make_float4(acc2[i][0], acc2[i][1], acc2[i][2], acc2[i][3]);
                float4 hi = make_float4(acc2[i][4], acc2[i][5], acc2[i][6], acc2[i][7]);
                size_t o = (size_t)gn * HIDF + c0;
                *(float4*)&h_out[o] = lo;
                *(float4*)&h_out[o + 4] = hi;
                if (WRITE_ZB) { *(float4*)&zb_out[o] = lo; *(float4*)&zb_out[o + 4] = hi; }
            }
        }
    }
}

// ---------------------------------------------------------------------------
extern "C" void kernel_launch(void* const* d_in, const int* in_sizes, int n_in,
                              void* d_out, int out_size, void* d_ws, size_t ws_size,
                              hipStream_t stream) {
    const int*   feats = (const int*)d_in[0];
    const int*   src   = (const int*)d_in[1];
    const int*   dst   = (const int*)d_in[2];
    const int*   gid   = (const int*)d_in[3];
    const float* emb   = (const float*)d_in[4];
    const float* W1    = (const float*)d_in[5];
    const float* b1    = (const float*)d_in[6];
    const float* W2    = (const float*)d_in[7];
    const float* b2    = (const float*)d_in[8];
    const float* Wr    = (const float*)d_in[9];
    float* out = (float*)d_out;

    float* h  = (float*)d_ws;                          // 12.8 MB
    float* zb = h + (size_t)NNODES * HIDF;             // 12.8 MB
    int* deg    = (int*)(zb + (size_t)NNODES * HIDF);
    int* off    = deg + NNODES;                        // NNODES+1
    int* cursor = off + NNODES + 1;
    int* bsum   = cursor + NNODES;                     // NBLK
    int* bofs   = bsum + NBLK;                         // NBLK
    int* csr    = bofs + NBLK;                         // NEDGES

    size_t need = (size_t)(2 * NNODES * HIDF) * sizeof(float) +
                  (size_t)(3 * NNODES + 1 + 2 * NBLK + NEDGES) * sizeof(int);
    const bool use_csr = ws_size >= need;              // constant: capture-safe

    const int mlp_grid = (NNODES + 127) / 128;         // 391

    if (use_csr) {
        // ---- CSR build (once, reused by all 3 layers) ----
        hipMemsetAsync(deg, 0, NNODES * sizeof(int), stream);
        k_hist<<<(NEDGES + 255) / 256, 256, 0, stream>>>(dst, deg);
        k_scan1<<<NBLK, 256, 0, stream>>>(deg, off, bsum);
        k_scan2<<<1, 256, 0, stream>>>(bsum, bofs, off);
        k_scan3<<<NBLK, 256, 0, stream>>>(off, bofs, cursor);
        k_bucket<<<(NEDGES + 255) / 256, 256, 0, stream>>>(src, dst, cursor, csr);

        const int agg_grid = (NNODES * HIDF + 255) / 256;
        // layer 0 (agg reads emb directly; no k_embed)
        k_agg<1><<<agg_grid, 256, 0, stream>>>(off, csr, nullptr, feats, emb, zb);
        k_mlp<0, 0><<<mlp_grid, 128, 0, stream>>>(zb, W1, b1, W2, b2,
                                                  h, nullptr, nullptr, nullptr, nullptr);
        // layer 1
        k_agg<0><<<agg_grid, 256, 0, stream>>>(off, csr, h, nullptr, nullptr, zb);
        k_mlp<0, 0><<<mlp_grid, 128, 0, stream>>>(zb, W1 + 4096, b1 + 64, W2 + 4096, b2 + 64,
                                                  h, nullptr, nullptr, nullptr, nullptr);
        // layer 2 + fused pool/head
        k_agg<0><<<agg_grid, 256, 0, stream>>>(off, csr, h, nullptr, nullptr, zb);
        hipMemsetAsync(out, 0, NGRAPHS * sizeof(float), stream);
        k_mlp<1, 0><<<mlp_grid, 128, 0, stream>>>(zb, W1 + 8192, b1 + 128, W2 + 8192, b2 + 128,
                                                  nullptr, nullptr, Wr, gid, out);
    } else {
        // ---- fallback: atomic scatter path ----
        k_embed<<<(NNODES * HIDF + 255) / 256, 256, 0, stream>>>(feats, emb, h, zb);
        for (int l = 0; l < 3; ++l) {
            k_scatter<<<25000, 256, 0, stream>>>(src, dst, h, zb);
            if (l < 2) {
                k_mlp<0, 1><<<mlp_grid, 128, 0, stream>>>(zb, W1 + l * 4096, b1 + l * 64,
                                                          W2 + l * 4096, b2 + l * 64,
                                                          h, zb, nullptr, nullptr, nullptr);
            } else {
                hipMemsetAsync(out, 0, NGRAPHS * sizeof(float), stream);
                k_mlp<1, 0><<<mlp_grid, 128, 0, stream>>>(zb, W1 + l * 4096, b1 + l * 64,
                                                          W2 + l * 4096, b2 + l * 64,
                                                          nullptr, nullptr, Wr, gid, out);
            }
        }
    }
}

// Round 12
// 330.361 us; speedup vs baseline: 2.9752x; 1.0604x over previous
//
#include <hip/hip_runtime.h>

#define NNODES 50000
#define NEDGES 800000
#define NGRAPHS 128
#define HIDF 64
#define ZSTR 128            // zT row stride (floats); banks fixed by XOR swizzle
#define NBLK 196            // ceil(50000/256) scan blocks

// ---------------------------------------------------------------------------
// Fallback-only kernels (used if ws_size too small for CSR; never expected).
// ---------------------------------------------------------------------------
__global__ __launch_bounds__(256) void k_embed(const int* __restrict__ feats,
                                               const float* __restrict__ emb,
                                               float* __restrict__ h,
                                               float* __restrict__ zb) {
    int t = blockIdx.x * blockDim.x + threadIdx.x;
    if (t >= NNODES * HIDF) return;
    float v = emb[feats[t >> 6] * HIDF + (t & 63)];
    h[t] = v;
    zb[t] = v;
}

__global__ __launch_bounds__(256) void k_scatter(const int* __restrict__ src,
                                                 const int* __restrict__ dst,
                                                 const float* __restrict__ h,
                                                 float* zb) {
    int wave = (blockIdx.x * blockDim.x + threadIdx.x) >> 6;
    int c = threadIdx.x & 63;
    int nwaves = (gridDim.x * blockDim.x) >> 6;
    for (int e = wave; e < NEDGES; e += nwaves)
        atomicAdd(&zb[dst[e] * HIDF + c], h[src[e] * HIDF + c]);
}

// ---------------------------------------------------------------------------
// CSR build: hist -> 3-stage multi-block exclusive scan -> bucket fill.
// k_bucket R11 counters: 48us, WRITE_SIZE 52.6MB (= 800K x 64B line
// writebacks for 3.2MB payload) -> write-allocate scatter bound. Radix-binned
// rewrite is the R13 candidate if it remains top after agg shrinks.
// ---------------------------------------------------------------------------
__global__ __launch_bounds__(256) void k_hist(const int* __restrict__ dst,
                                              int* __restrict__ deg) {
    int t = blockIdx.x * blockDim.x + threadIdx.x;
    if (t < NEDGES) atomicAdd(&deg[dst[t]], 1);
}

__global__ __launch_bounds__(256) void k_scan1(const int* __restrict__ deg,
                                               int* __restrict__ off,
                                               int* __restrict__ bsum) {
    __shared__ int buf[256];
    const int t = threadIdx.x;
    int i = blockIdx.x * 256 + t;
    int v = (i < NNODES) ? deg[i] : 0;
    buf[t] = v;
    __syncthreads();
#pragma unroll
    for (int s = 1; s < 256; s <<= 1) {
        int add = (t >= s) ? buf[t - s] : 0;
        __syncthreads();
        buf[t] += add;
        __syncthreads();
    }
    if (i < NNODES) off[i] = buf[t] - v;          // block-local exclusive
    if (t == 255) bsum[blockIdx.x] = buf[255];
}

__global__ __launch_bounds__(256) void k_scan2(const int* __restrict__ bsum,
                                               int* __restrict__ bofs,
                                               int* __restrict__ off) {
    __shared__ int buf[256];
    const int t = threadIdx.x;
    int v = (t < NBLK) ? bsum[t] : 0;
    buf[t] = v;
    __syncthreads();
#pragma unroll
    for (int s = 1; s < 256; s <<= 1) {
        int add = (t >= s) ? buf[t - s] : 0;
        __syncthreads();
        buf[t] += add;
        __syncthreads();
    }
    if (t < NBLK) bofs[t] = buf[t] - v;           // exclusive block offsets
    if (t == 255) off[NNODES] = buf[255];         // total = NEDGES
}

__global__ __launch_bounds__(256) void k_scan3(int* __restrict__ off,
                                               const int* __restrict__ bofs,
                                               int* __restrict__ cursor) {
    int i = blockIdx.x * 256 + threadIdx.x;
    if (i < NNODES) {
        int o = off[i] + bofs[blockIdx.x];
        off[i] = o;
        cursor[i] = o;                            // bucket cursors (no memcpy)
    }
}

__global__ __launch_bounds__(256) void k_bucket(const int* __restrict__ src,
                                                const int* __restrict__ dst,
                                                int* __restrict__ cursor,
                                                int* __restrict__ csr) {
    int t = blockIdx.x * blockDim.x + threadIdx.x;
    if (t < NEDGES) {
        int pos = atomicAdd(&cursor[dst[t]], 1);
        csr[pos] = src[t];
    }
}

// ---------------------------------------------------------------------------
// Pull-mode aggregate: TWO nodes per wave, combined contiguous csr range
// [off(2w), off(2w+2)), unroll x8.
// R5->R11 A/B confirmed latency-bound gather chain (unroll x4: 75->~45us).
// Within-node unroll gives no ILP for deg<4 nodes; pairing nodes gives
// guaranteed cross-node independence -> up to 8 row-gathers in flight.
// Accumulator split by wave-uniform (e+i < eM) select (cheap: 2 cndmask+add;
// VALUBusy was 12.8%). 3 offset loads per 2 nodes (ranges are adjacent).
// FIRST=1 reads emb[feats[.]] directly (emb 25.6KB L1-resident; no k_embed).
// ---------------------------------------------------------------------------
template <int FIRST>
__global__ __launch_bounds__(256) void k_agg(const int* __restrict__ off,
                                             const int* __restrict__ csr,
                                             const float* __restrict__ hsrc,
                                             const int* __restrict__ feats,
                                             const float* __restrict__ emb,
                                             float* __restrict__ zb) {
    int wave = (blockIdx.x * blockDim.x + threadIdx.x) >> 6;
    int c = threadIdx.x & 63;
    if (wave >= NNODES / 2) return;
    const int n0 = wave * 2, n1 = n0 + 1;
    const int eS = off[n0], eM = off[n1], eE = off[n1 + 1];

    float acc0 = FIRST ? emb[feats[n0] * HIDF + c] : hsrc[(size_t)n0 * HIDF + c];
    float acc1 = FIRST ? emb[feats[n1] * HIDF + c] : hsrc[(size_t)n1 * HIDF + c];

    int e = eS;
    for (; e + 8 <= eE; e += 8) {
        int s[8];
        float v[8];
#pragma unroll
        for (int i = 0; i < 8; ++i) s[i] = csr[e + i];
#pragma unroll
        for (int i = 0; i < 8; ++i)
            v[i] = FIRST ? emb[feats[s[i]] * HIDF + c]
                         : hsrc[(size_t)s[i] * HIDF + c];
#pragma unroll
        for (int i = 0; i < 8; ++i) {
            bool a = (e + i) < eM;                // wave-uniform split
            acc0 += a ? v[i] : 0.f;
            acc1 += a ? 0.f : v[i];
        }
    }
    for (; e < eE; ++e) {
        int s = csr[e];
        float v = FIRST ? emb[feats[s] * HIDF + c]
                        : hsrc[(size_t)s * HIDF + c];
        bool a = e < eM;
        acc0 += a ? v : 0.f;
        acc1 += a ? 0.f : v;
    }
    zb[(size_t)n0 * HIDF + c] = acc0;
    zb[(size_t)n1 * HIDF + c] = acc1;
}

// ---------------------------------------------------------------------------
// Register-tiled fused MLP (unchanged from R5): 128 threads/block, 128 nodes.
// Thread (tx,ty) computes an 8-node x 8-channel tile -> VALU-bound.
// Activations transposed+XOR-swizzled in LDS; all accesses <=2-way (free).
// FINAL=1 fuses SumPool+head: tx-shfl reduce -> LDS pool -> sparse flush.
// ---------------------------------------------------------------------------
template <int FINAL, int WRITE_ZB>
__global__ __launch_bounds__(128) void k_mlp(const float* __restrict__ zin,
                                             const float* __restrict__ W1,
                                             const float* __restrict__ b1,
                                             const float* __restrict__ W2,
                                             const float* __restrict__ b2,
                                             float* __restrict__ h_out,
                                             float* __restrict__ zb_out,
                                             const float* __restrict__ Wr,
                                             const int* __restrict__ gid,
                                             float* __restrict__ out) {
    __shared__ float zt[HIDF * ZSTR];                 // 32 KB transposed acts
    __shared__ float sW1[HIDF * HIDF];                // 16 KB
    __shared__ float sW2[HIDF * HIDF];                // 16 KB
    __shared__ float sbb[3 * HIDF];                   // b1 | b2 | Wr
    __shared__ float pool[NGRAPHS];

    const int t = threadIdx.x;
    const int base = blockIdx.x * 128;

    for (int i = t; i < 1024; i += 128) {
        ((float4*)sW1)[i] = ((const float4*)W1)[i];
        ((float4*)sW2)[i] = ((const float4*)W2)[i];
    }
    if (t < 64) { sbb[t] = b1[t]; sbb[64 + t] = b2[t]; }
    if (FINAL) {
        if (t >= 64) sbb[64 + t] = Wr[t - 64];        // sbb[128..191]
        pool[t] = 0.f;
    }

    for (int it = 0; it < 16; ++it) {
        int idx = it * 128 + t;
        int nb = idx >> 4;                            // node-in-block 0..127
        int c0 = (idx & 15) * 4;
        int gn = base + nb;
        float4 v = (gn < NNODES) ? *(const float4*)&zin[(size_t)gn * HIDF + c0]
                                 : make_float4(0.f, 0.f, 0.f, 0.f);
        int sw = ((idx & 15) >> 1) << 2;              // == ((c0+i)>>3)<<2, i<4
        int nsw = nb ^ sw;
        zt[(c0 + 0) * ZSTR + nsw] = v.x;
        zt[(c0 + 1) * ZSTR + nsw] = v.y;
        zt[(c0 + 2) * ZSTR + nsw] = v.z;
        zt[(c0 + 3) * ZSTR + nsw] = v.w;
    }
    __syncthreads();

    const int tx = t & 7, ty = t >> 3;
    const int c0 = tx * 8, n0 = ty * 8;

    // ---- layer A: z2 = relu(z @ W1 + b1) ----
    float acc[8][8];
#pragma unroll
    for (int j = 0; j < 8; ++j) {
        float b = sbb[c0 + j];
#pragma unroll
        for (int i = 0; i < 8; ++i) acc[i][j] = b;
    }
    for (int k8 = 0; k8 < 8; ++k8) {
        const int x0 = n0 ^ (k8 << 2);                // hoisted swizzle
        const int x4 = (n0 + 4) ^ (k8 << 2);
#pragma unroll
        for (int kk = 0; kk < 8; ++kk) {
            int k = k8 * 8 + kk;
            float4 z0 = *(const float4*)&zt[k * ZSTR + x0];
            float4 z1 = *(const float4*)&zt[k * ZSTR + x4];
            float4 w0 = *(const float4*)&sW1[k * HIDF + c0];
            float4 w1 = *(const float4*)&sW1[k * HIDF + c0 + 4];
            float zv[8] = {z0.x, z0.y, z0.z, z0.w, z1.x, z1.y, z1.z, z1.w};
            float wv[8] = {w0.x, w0.y, w0.z, w0.w, w1.x, w1.y, w1.z, w1.w};
#pragma unroll
            for (int i = 0; i < 8; ++i)
#pragma unroll
                for (int j = 0; j < 8; ++j)
                    acc[i][j] = fmaf(zv[i], wv[j], acc[i][j]);
        }
    }
    __syncthreads();                                   // all zt reads done

    {
        const int wx0 = n0 ^ (tx << 2);               // ((c0+j)>>3)==tx
        const int wx4 = (n0 + 4) ^ (tx << 2);
#pragma unroll
        for (int j = 0; j < 8; ++j) {
            int c = c0 + j;
            *(float4*)&zt[c * ZSTR + wx0] =
                make_float4(fmaxf(acc[0][j], 0.f), fmaxf(acc[1][j], 0.f),
                            fmaxf(acc[2][j], 0.f), fmaxf(acc[3][j], 0.f));
            *(float4*)&zt[c * ZSTR + wx4] =
                make_float4(fmaxf(acc[4][j], 0.f), fmaxf(acc[5][j], 0.f),
                            fmaxf(acc[6][j], 0.f), fmaxf(acc[7][j], 0.f));
        }
    }
    __syncthreads();

    // ---- layer B: hnext = z2 @ W2 + b2 ----
    float acc2[8][8];
#pragma unroll
    for (int j = 0; j < 8; ++j) {
        float b = sbb[64 + c0 + j];
#pragma unroll
        for (int i = 0; i < 8; ++i) acc2[i][j] = b;
    }
    for (int k8 = 0; k8 < 8; ++k8) {
        const int x0 = n0 ^ (k8 << 2);
        const int x4 = (n0 + 4) ^ (k8 << 2);
#pragma unroll
        for (int kk = 0; kk < 8; ++kk) {
            int k = k8 * 8 + kk;
            float4 z0 = *(const float4*)&zt[k * ZSTR + x0];
            float4 z1 = *(const float4*)&zt[k * ZSTR + x4];
            float4 w0 = *(const float4*)&sW2[k * HIDF + c0];
            float4 w1 = *(const float4*)&sW2[k * HIDF + c0 + 4];
            float zv[8] = {z0.x, z0.y, z0.z, z0.w, z1.x, z1.y, z1.z, z1.w};
            float wv[8] = {w0.x, w0.y, w0.z, w0.w, w1.x, w1.y, w1.z, w1.w};
#pragma unroll
            for (int i = 0; i < 8; ++i)
#pragma unroll
                for (int j = 0; j < 8; ++j)
                    acc2[i][j] = fmaf(zv[i], wv[j], acc2[i][j]);
        }
    }

    if (FINAL) {
#pragma unroll
        for (int i = 0; i < 8; ++i) {
            float pr = 0.f;
#pragma unroll
            for (int j = 0; j < 8; ++j) pr = fmaf(acc2[i][j], sbb[128 + c0 + j], pr);
#pragma unroll
            for (int o = 1; o < 8; o <<= 1) pr += __shfl_xor(pr, o);
            if (tx == 0) {
                int gn = base + n0 + i;
                if (gn < NNODES) atomicAdd(&pool[gid[gn]], pr);
            }
        }
        __syncthreads();
        float p = pool[t];
        if (p != 0.f) atomicAdd(&out[t], p);          // adding 0 is a no-op
    } else {
#pragma unroll
        for (int i = 0; i < 8; ++i) {
            int gn = base + n0 + i;
            if (gn < NNODES) {
                float4 lo = make_float4(acc2[i][0], acc2[i][1], acc2[i][2], acc2[i][3]);
                float4 hi = make_float4(acc2[i][4], acc2[i][5], acc2[i][6], acc2[i][7]);
                size_t o = (size_t)gn * HIDF + c0;
                *(float4*)&h_out[o] = lo;
                *(float4*)&h_out[o + 4] = hi;
                if (WRITE_ZB) { *(float4*)&zb_out[o] = lo; *(float4*)&zb_out[o + 4] = hi; }
            }
        }
    }
}

// ---------------------------------------------------------------------------
extern "C" void kernel_launch(void* const* d_in, const int* in_sizes, int n_in,
                              void* d_out, int out_size, void* d_ws, size_t ws_size,
                              hipStream_t stream) {
    const int*   feats = (const int*)d_in[0];
    const int*   src   = (const int*)d_in[1];
    const int*   dst   = (const int*)d_in[2];
    const int*   gid   = (const int*)d_in[3];
    const float* emb   = (const float*)d_in[4];
    const float* W1    = (const float*)d_in[5];
    const float* b1    = (const float*)d_in[6];
    const float* W2    = (const float*)d_in[7];
    const float* b2    = (const float*)d_in[8];
    const float* Wr    = (const float*)d_in[9];
    float* out = (float*)d_out;

    float* h  = (float*)d_ws;                          // 12.8 MB
    float* zb = h + (size_t)NNODES * HIDF;             // 12.8 MB
    int* deg    = (int*)(zb + (size_t)NNODES * HIDF);
    int* off    = deg + NNODES;                        // NNODES+1
    int* cursor = off + NNODES + 1;
    int* bsum   = cursor + NNODES;                     // NBLK
    int* bofs   = bsum + NBLK;                         // NBLK
    int* csr    = bofs + NBLK;                         // NEDGES

    size_t need = (size_t)(2 * NNODES * HIDF) * sizeof(float) +
                  (size_t)(3 * NNODES + 1 + 2 * NBLK + NEDGES) * sizeof(int);
    const bool use_csr = ws_size >= need;              // constant: capture-safe

    const int mlp_grid = (NNODES + 127) / 128;         // 391

    if (use_csr) {
        // ---- CSR build (once, reused by all 3 layers) ----
        hipMemsetAsync(deg, 0, NNODES * sizeof(int), stream);
        k_hist<<<(NEDGES + 255) / 256, 256, 0, stream>>>(dst, deg);
        k_scan1<<<NBLK, 256, 0, stream>>>(deg, off, bsum);
        k_scan2<<<1, 256, 0, stream>>>(bsum, bofs, off);
        k_scan3<<<NBLK, 256, 0, stream>>>(off, bofs, cursor);
        k_bucket<<<(NEDGES + 255) / 256, 256, 0, stream>>>(src, dst, cursor, csr);

        const int agg_grid = ((NNODES / 2) * HIDF + 255) / 256;   // 12500 blocks
        // layer 0 (agg reads emb directly; no k_embed)
        k_agg<1><<<agg_grid, 256, 0, stream>>>(off, csr, nullptr, feats, emb, zb);
        k_mlp<0, 0><<<mlp_grid, 128, 0, stream>>>(zb, W1, b1, W2, b2,
                                                  h, nullptr, nullptr, nullptr, nullptr);
        // layer 1
        k_agg<0><<<agg_grid, 256, 0, stream>>>(off, csr, h, nullptr, nullptr, zb);
        k_mlp<0, 0><<<mlp_grid, 128, 0, stream>>>(zb, W1 + 4096, b1 + 64, W2 + 4096, b2 + 64,
                                                  h, nullptr, nullptr, nullptr, nullptr);
        // layer 2 + fused pool/head
        k_agg<0><<<agg_grid, 256, 0, stream>>>(off, csr, h, nullptr, nullptr, zb);
        hipMemsetAsync(out, 0, NGRAPHS * sizeof(float), stream);
        k_mlp<1, 0><<<mlp_grid, 128, 0, stream>>>(zb, W1 + 8192, b1 + 128, W2 + 8192, b2 + 128,
                                                  nullptr, nullptr, Wr, gid, out);
    } else {
        // ---- fallback: atomic scatter path ----
        k_embed<<<(NNODES * HIDF + 255) / 256, 256, 0, stream>>>(feats, emb, h, zb);
        for (int l = 0; l < 3; ++l) {
            k_scatter<<<25000, 256, 0, stream>>>(src, dst, h, zb);
            if (l < 2) {
                k_mlp<0, 1><<<mlp_grid, 128, 0, stream>>>(zb, W1 + l * 4096, b1 + l * 64,
                                                          W2 + l * 4096, b2 + l * 64,
                                                          h, zb, nullptr, nullptr, nullptr);
            } else {
                hipMemsetAsync(out, 0, NGRAPHS * sizeof(float), stream);
                k_mlp<1, 0><<<mlp_grid, 128, 0, stream>>>(zb, W1 + l * 4096, b1 + l * 64,
                                                          W2 + l * 4096, b2 + l * 64,
                                                          nullptr, nullptr, Wr, gid, out);
            }
        }
    }
}